// Round 8
// baseline (337.776 us; speedup 1.0000x reference)
//
#include <hip/hip_runtime.h>

typedef float v2f __attribute__((ext_vector_type(2)));

#define NW 64
#define NP 32            // worker pairs
#define MAX_EVALS 8
#define FREEZE_TOL 7e-3f
// Freeze fires AFTER the step is applied. Lanes that freeze are on the
// superlinear (Newton/secant-in-bracket) path: post-step residual ~
// kappa*st*e_prev ~ 6e-4, NOT st. Bisection-fallback lanes take huge steps
// and never freeze early. tol 1e-3 -> 4.5e-3 left absmax unchanged (3.9e-3),
// confirming the model; 7e-3 converts most E=3 waves to E=2.

// (256,5): 5 blocks/CU -> 5 waves/SIMD, VGPR cap ~102. Live set: v[]=64 +
// state ~10 + capped-unroll temps ~20 ~= 95. (256,4) measured 119us with
// ~80% load/compute overlap; 5 waves -> ~87%.
__global__ __launch_bounds__(256, 5) void damed_median_kernel(
    const float* __restrict__ y, float* __restrict__ out, int D) {
  int d = blockIdx.x * blockDim.x + threadIdx.x;
  if (d >= D) return;

  // 64 worker values as 32 register pairs (VOP3P operands).
  // y[w][d]: stride-D across w, coalesced across lanes in d.
  v2f v[NP];
  v2f vmin = {3.4e38f, 3.4e38f}, vmax = {-3.4e38f, -3.4e38f}, sum2 = {0.f, 0.f};
#pragma unroll
  for (int p = 0; p < NP; ++p) {
    v2f t;
    t.x = y[(size_t)(2 * p) * (size_t)D + (size_t)d];
    t.y = y[(size_t)(2 * p + 1) * (size_t)D + (size_t)d];
    v[p] = t;
    vmin = __builtin_elementwise_min(vmin, t);
    vmax = __builtin_elementwise_max(vmax, t);
    sum2 += t;
  }
  float xl = fminf(vmin.x, vmin.y);
  float xg = fmaxf(vmax.x, vmax.y);
  float x = (sum2.x + sum2.y) * (1.0f / NW);
  x = fminf(fmaxf(x, xl), xg);

  // A&S 7.1.27: erf(a) = 1 - q(a)^-4, q = 1 + b1 a + b2 a^2 + b3 a^3 + b4 a^4,
  // |err| <= 5e-4, no exp. Derivative of the approx: 4 q^-5 q'(a), used ONCE
  // (eval A); later evals use the free secant slope.
  const float B1 = 0.278393f, B2 = 0.230389f, B3 = 0.000972f, B4 = 0.078108f;
  const v2f one2 = {1.f, 1.f};
  const v2f Q1 = {B1, B1}, Q2 = {B2, B2}, Q3 = {B3, B3}, Q4 = {B4, B4};
  const v2f P1 = {B1, B1}, P2 = {2 * B2, 2 * B2};
  const v2f P3 = {3 * B3, 3 * B3}, P4 = {4 * B4, 4 * B4};

  // Value-only eval: fm(xc) = sum_w erf(v_w - xc).
  // fabs as pk_max(t,-t): 1 VOP3P vs 2 scalar v_and per pair.
  // unroll 4 caps concurrent live chains (VGPR budget for 5 waves/SIMD).
  auto evalF = [&](float xc) -> float {
    v2f fmA = {0.f, 0.f}, fmB = {0.f, 0.f};
    v2f nx = {-xc, -xc};
#pragma unroll 4
    for (int p = 0; p < NP; p += 2) {
      v2f tA = v[p] + nx;
      v2f tB = v[p + 1] + nx;
      v2f aA = __builtin_elementwise_max(tA, -tA);
      v2f aB = __builtin_elementwise_max(tB, -tB);
      v2f qA = __builtin_elementwise_fma(aA, Q4, Q3);
      v2f qB = __builtin_elementwise_fma(aB, Q4, Q3);
      qA = __builtin_elementwise_fma(aA, qA, Q2);
      qB = __builtin_elementwise_fma(aB, qB, Q2);
      qA = __builtin_elementwise_fma(aA, qA, Q1);
      qB = __builtin_elementwise_fma(aB, qB, Q1);
      qA = __builtin_elementwise_fma(aA, qA, one2);
      qB = __builtin_elementwise_fma(aB, qB, one2);
      v2f rA, rB;
      rA.x = __builtin_amdgcn_rcpf(qA.x); rA.y = __builtin_amdgcn_rcpf(qA.y);
      rB.x = __builtin_amdgcn_rcpf(qB.x); rB.y = __builtin_amdgcn_rcpf(qB.y);
      rA = rA * rA; rB = rB * rB;   // q^-2
      rA = rA * rA; rB = rB * rB;   // q^-4
      v2f eA = one2 - rA;
      v2f eB = one2 - rB;
      eA.x = __builtin_copysignf(eA.x, tA.x); eA.y = __builtin_copysignf(eA.y, tA.y);
      eB.x = __builtin_copysignf(eB.x, tB.x); eB.y = __builtin_copysignf(eB.y, tB.y);
      fmA += eA; fmB += eB;
    }
    v2f s = fmA + fmB;
    return s.x + s.y;
  };

  // ---- eval A: value + analytic derivative -> one true Newton step. ----
  float fm0, fd0;
  {
    v2f fmA = {0.f, 0.f}, fmB = {0.f, 0.f}, fdA = {0.f, 0.f}, fdB = {0.f, 0.f};
    v2f nx = {-x, -x};
#pragma unroll 4
    for (int p = 0; p < NP; p += 2) {
      v2f tA = v[p] + nx;
      v2f tB = v[p + 1] + nx;
      v2f aA = __builtin_elementwise_max(tA, -tA);
      v2f aB = __builtin_elementwise_max(tB, -tB);
      v2f qA = __builtin_elementwise_fma(aA, Q4, Q3);
      v2f qB = __builtin_elementwise_fma(aB, Q4, Q3);
      qA = __builtin_elementwise_fma(aA, qA, Q2);
      qB = __builtin_elementwise_fma(aB, qB, Q2);
      qA = __builtin_elementwise_fma(aA, qA, Q1);
      qB = __builtin_elementwise_fma(aB, qB, Q1);
      qA = __builtin_elementwise_fma(aA, qA, one2);
      qB = __builtin_elementwise_fma(aB, qB, one2);
      v2f dA = __builtin_elementwise_fma(aA, P4, P3);
      v2f dB = __builtin_elementwise_fma(aB, P4, P3);
      dA = __builtin_elementwise_fma(aA, dA, P2);
      dB = __builtin_elementwise_fma(aB, dB, P2);
      dA = __builtin_elementwise_fma(aA, dA, P1);
      dB = __builtin_elementwise_fma(aB, dB, P1);
      v2f rA, rB;
      rA.x = __builtin_amdgcn_rcpf(qA.x); rA.y = __builtin_amdgcn_rcpf(qA.y);
      rB.x = __builtin_amdgcn_rcpf(qB.x); rB.y = __builtin_amdgcn_rcpf(qB.y);
      v2f r2A = rA * rA, r2B = rB * rB;
      v2f r4A = r2A * r2A, r4B = r2B * r2B;
      v2f r5A = r4A * rA, r5B = r4B * rB;
      fdA = __builtin_elementwise_fma(r5A, dA, fdA);
      fdB = __builtin_elementwise_fma(r5B, dB, fdB);
      v2f eA = one2 - r4A;
      v2f eB = one2 - r4B;
      eA.x = __builtin_copysignf(eA.x, tA.x); eA.y = __builtin_copysignf(eA.y, tA.y);
      eB.x = __builtin_copysignf(eB.x, tB.x); eB.y = __builtin_copysignf(eB.y, tB.y);
      fmA += eA; fmB += eB;
    }
    v2f fm2 = fmA + fmB, fd2 = fdA + fdB;
    fm0 = fm2.x + fm2.y;
    fd0 = 4.0f * (fd2.x + fd2.y);  // |f'| of the approx, strictly > 0
  }
  // f decreasing: fm>0 => root above x.
  if (fm0 > 0.f) xl = x; else xg = x;
  float xn = x + fm0 * __builtin_amdgcn_rcpf(fd0);
  bool ok = (xn >= xl) && (xn <= xg);  // non-strict (round-1 lesson); NaN->bisect
  float cand = ok ? xn : 0.5f * (xl + xg);
  bool frozen = (__builtin_fabsf(cand - x) <= FREEZE_TOL);
  float xprev = x, fmprev = fm0;
  x = cand;

  // ---- secant refinement: derivative comes free from (xprev, fmprev). ----
#pragma unroll 1
  for (int e = 1; e < MAX_EVALS; ++e) {
    if (__all(frozen)) break;  // wave-uniform, deterministic for fixed input
    float fmc = evalF(x);
    if (fmc > 0.f) xl = x; else xg = x;
    float xs = x + fmc * (x - xprev) / (fmprev - fmc);  // secant step
    bool ok2 = (xs >= xl) && (xs <= xg);                // NaN/flat -> bisect
    float cand2 = ok2 ? xs : 0.5f * (xl + xg);
    float st = __builtin_fabsf(cand2 - x);
    // fmc==0: x IS the root; freeze (guards exact-zero -> 0/0 -> midpoint hop).
    bool done = (st <= FREEZE_TOL) || (fmc == 0.f);
    float xnew = frozen ? x : cand2;   // frozen lanes do not move
    xprev = frozen ? xprev : x;
    fmprev = frozen ? fmprev : fmc;
    frozen = frozen || done;
    x = xnew;
  }
  out[d] = x;
}

extern "C" void kernel_launch(void* const* d_in, const int* in_sizes, int n_in,
                              void* d_out, int out_size, void* d_ws, size_t ws_size,
                              hipStream_t stream) {
  const float* y = (const float*)d_in[0];
  float* out = (float*)d_out;
  const int D = out_size;  // 2^21 coordinates
  const int threads = 256;
  const int blocks = (D + threads - 1) / threads;
  damed_median_kernel<<<blocks, threads, 0, stream>>>(y, out, D);
}

// Round 9
// 117.422 us; speedup vs baseline: 2.8766x; 2.8766x over previous
//
#include <hip/hip_runtime.h>

typedef float v2f __attribute__((ext_vector_type(2)));

#define NW 64
#define NP 32            // worker pairs
#define MAX_EVALS 8
#define FREEZE_TOL 7e-3f
// Freeze fires AFTER the step is applied; frozen lanes are on the superlinear
// path, post-step residual ~ kappa*st*e_prev << st. absmax has been 3.9e-3
// (A&S bias floor) for tol = 1e-3, 4.5e-3, 7e-3 alike -- tolerance-invariant.

// (256,4): VGPR cap ~128. Round-8 lesson: (256,5) squeezed the cap below the
// v[64] live set -> full array spill (VGPR 32, FETCH 262->773 MB, VALUBusy
// 96->21%, 3x slower). Do NOT raise the wave target on this kernel.
__global__ __launch_bounds__(256, 4) void damed_median_kernel(
    const float* __restrict__ y, float* __restrict__ out, int D) {
  int d = blockIdx.x * blockDim.x + threadIdx.x;
  if (d >= D) return;

  // 64 worker values as 32 register pairs (VOP3P operands).
  // y[w][d]: stride-D across w, coalesced across lanes in d.
  v2f v[NP];
  v2f vmin = {3.4e38f, 3.4e38f}, vmax = {-3.4e38f, -3.4e38f}, sum2 = {0.f, 0.f};
#pragma unroll
  for (int p = 0; p < NP; ++p) {
    v2f t;
    t.x = y[(size_t)(2 * p) * (size_t)D + (size_t)d];
    t.y = y[(size_t)(2 * p + 1) * (size_t)D + (size_t)d];
    v[p] = t;
    vmin = __builtin_elementwise_min(vmin, t);
    vmax = __builtin_elementwise_max(vmax, t);
    sum2 += t;
  }
  float xl = fminf(vmin.x, vmin.y);
  float xg = fmaxf(vmax.x, vmax.y);
  float x = (sum2.x + sum2.y) * (1.0f / NW);
  x = fminf(fmaxf(x, xl), xg);

  // A&S 7.1.27: erf(a) = 1 - q(a)^-4, q = 1 + b1 a + b2 a^2 + b3 a^3 + b4 a^4,
  // |err| <= 5e-4, no exp. Derivative of the approx: 4 q^-5 q'(a), used ONCE
  // (eval A); later evals use the free secant slope.
  const float B1 = 0.278393f, B2 = 0.230389f, B3 = 0.000972f, B4 = 0.078108f;
  const v2f one2 = {1.f, 1.f};
  const v2f Q1 = {B1, B1}, Q2 = {B2, B2}, Q3 = {B3, B3}, Q4 = {B4, B4};
  const v2f P1 = {B1, B1}, P2 = {2 * B2, 2 * B2};
  const v2f P3 = {3 * B3, 3 * B3}, P4 = {4 * B4, 4 * B4};

  // Value-only eval: fm(xc) = sum_w erf(v_w - xc); 2x2-way split chains.
  auto evalF = [&](float xc) -> float {
    v2f fmA = {0.f, 0.f}, fmB = {0.f, 0.f};
    v2f nx = {-xc, -xc};
#pragma unroll
    for (int p = 0; p < NP; p += 2) {
      v2f tA = v[p] + nx;
      v2f tB = v[p + 1] + nx;
      v2f aA = __builtin_elementwise_max(tA, -tA);
      v2f aB = __builtin_elementwise_max(tB, -tB);
      v2f qA = __builtin_elementwise_fma(aA, Q4, Q3);
      v2f qB = __builtin_elementwise_fma(aB, Q4, Q3);
      qA = __builtin_elementwise_fma(aA, qA, Q2);
      qB = __builtin_elementwise_fma(aB, qB, Q2);
      qA = __builtin_elementwise_fma(aA, qA, Q1);
      qB = __builtin_elementwise_fma(aB, qB, Q1);
      qA = __builtin_elementwise_fma(aA, qA, one2);
      qB = __builtin_elementwise_fma(aB, qB, one2);
      v2f rA, rB;
      rA.x = __builtin_amdgcn_rcpf(qA.x); rA.y = __builtin_amdgcn_rcpf(qA.y);
      rB.x = __builtin_amdgcn_rcpf(qB.x); rB.y = __builtin_amdgcn_rcpf(qB.y);
      rA = rA * rA; rB = rB * rB;   // q^-2
      rA = rA * rA; rB = rB * rB;   // q^-4
      v2f eA = one2 - rA;
      v2f eB = one2 - rB;
      eA.x = __builtin_copysignf(eA.x, tA.x); eA.y = __builtin_copysignf(eA.y, tA.y);
      eB.x = __builtin_copysignf(eB.x, tB.x); eB.y = __builtin_copysignf(eB.y, tB.y);
      fmA += eA; fmB += eB;
    }
    v2f s = fmA + fmB;
    return s.x + s.y;
  };

  // ---- eval A: value + analytic derivative -> one true Newton step. ----
  float fm0, fd0;
  {
    v2f fmA = {0.f, 0.f}, fmB = {0.f, 0.f}, fdA = {0.f, 0.f}, fdB = {0.f, 0.f};
    v2f nx = {-x, -x};
#pragma unroll
    for (int p = 0; p < NP; p += 2) {
      v2f tA = v[p] + nx;
      v2f tB = v[p + 1] + nx;
      v2f aA = __builtin_elementwise_max(tA, -tA);
      v2f aB = __builtin_elementwise_max(tB, -tB);
      v2f qA = __builtin_elementwise_fma(aA, Q4, Q3);
      v2f qB = __builtin_elementwise_fma(aB, Q4, Q3);
      qA = __builtin_elementwise_fma(aA, qA, Q2);
      qB = __builtin_elementwise_fma(aB, qB, Q2);
      qA = __builtin_elementwise_fma(aA, qA, Q1);
      qB = __builtin_elementwise_fma(aB, qB, Q1);
      qA = __builtin_elementwise_fma(aA, qA, one2);
      qB = __builtin_elementwise_fma(aB, qB, one2);
      v2f dA = __builtin_elementwise_fma(aA, P4, P3);
      v2f dB = __builtin_elementwise_fma(aB, P4, P3);
      dA = __builtin_elementwise_fma(aA, dA, P2);
      dB = __builtin_elementwise_fma(aB, dB, P2);
      dA = __builtin_elementwise_fma(aA, dA, P1);
      dB = __builtin_elementwise_fma(aB, dB, P1);
      v2f rA, rB;
      rA.x = __builtin_amdgcn_rcpf(qA.x); rA.y = __builtin_amdgcn_rcpf(qA.y);
      rB.x = __builtin_amdgcn_rcpf(qB.x); rB.y = __builtin_amdgcn_rcpf(qB.y);
      v2f r2A = rA * rA, r2B = rB * rB;
      v2f r4A = r2A * r2A, r4B = r2B * r2B;
      v2f r5A = r4A * rA, r5B = r4B * rB;
      fdA = __builtin_elementwise_fma(r5A, dA, fdA);
      fdB = __builtin_elementwise_fma(r5B, dB, fdB);
      v2f eA = one2 - r4A;
      v2f eB = one2 - r4B;
      eA.x = __builtin_copysignf(eA.x, tA.x); eA.y = __builtin_copysignf(eA.y, tA.y);
      eB.x = __builtin_copysignf(eB.x, tB.x); eB.y = __builtin_copysignf(eB.y, tB.y);
      fmA += eA; fmB += eB;
    }
    v2f fm2 = fmA + fmB, fd2 = fdA + fdB;
    fm0 = fm2.x + fm2.y;
    fd0 = 4.0f * (fd2.x + fd2.y);  // |f'| of the approx, strictly > 0
  }
  // f decreasing: fm>0 => root above x.
  if (fm0 > 0.f) xl = x; else xg = x;
  float xn = x + fm0 * __builtin_amdgcn_rcpf(fd0);
  bool ok = (xn >= xl) && (xn <= xg);  // non-strict (round-1 lesson); NaN->bisect
  float cand = ok ? xn : 0.5f * (xl + xg);
  bool frozen = (__builtin_fabsf(cand - x) <= FREEZE_TOL);
  float xprev = x, fmprev = fm0;
  x = cand;

  // ---- secant refinement: derivative comes free from (xprev, fmprev). ----
#pragma unroll 1
  for (int e = 1; e < MAX_EVALS; ++e) {
    if (__all(frozen)) break;  // wave-uniform, deterministic for fixed input
    float fmc = evalF(x);
    if (fmc > 0.f) xl = x; else xg = x;
    float xs = x + fmc * (x - xprev) / (fmprev - fmc);  // secant step
    bool ok2 = (xs >= xl) && (xs <= xg);                // NaN/flat -> bisect
    float cand2 = ok2 ? xs : 0.5f * (xl + xg);
    float st = __builtin_fabsf(cand2 - x);
    // fmc==0: x IS the root; freeze (guards exact-zero -> 0/0 -> midpoint hop).
    bool done = (st <= FREEZE_TOL) || (fmc == 0.f);
    float xnew = frozen ? x : cand2;   // frozen lanes do not move
    xprev = frozen ? xprev : x;
    fmprev = frozen ? fmprev : fmc;
    frozen = frozen || done;
    x = xnew;
  }
  out[d] = x;
}

extern "C" void kernel_launch(void* const* d_in, const int* in_sizes, int n_in,
                              void* d_out, int out_size, void* d_ws, size_t ws_size,
                              hipStream_t stream) {
  const float* y = (const float*)d_in[0];
  float* out = (float*)d_out;
  const int D = out_size;  // 2^21 coordinates
  const int threads = 256;
  const int blocks = (D + threads - 1) / threads;
  damed_median_kernel<<<blocks, threads, 0, stream>>>(y, out, D);
}